// Round 4
// baseline (1323.880 us; speedup 1.0000x reference)
//
#include <hip/hip_runtime.h>

// ---------------------------------------------------------------------------
// MonarchMixerLayer fp32, B=32, N=D=1024, s=32.
//   p1 (per b, 32-wide d-tile): monarch(m1) -> relu(nk*) -> monarch(m2) -> xt
//   p2 (per b, 16-row n-tile):  monarch(m3) -> relu(dk*) -> monarch(m4) -> +xt -> LN
//
// Round-4 change: ONE vector per thread in monarch stages (X[32] scalar = 32
// VGPR live, ~50 total) -- round-3's float2 X[32] (64 live) forced
// spill/LDS-reread at VGPR_Count=64 (WRITE 352MB vs 128MB ideal, dur matched
// the LDS-reread cycle model). Stage A is now thread-local in-place (3
// barriers/monarch). p2 shrunk to 16-row tiles / 64KB LDS -> 2 blocks/CU for
// cross-block latency hiding.
//
// Monarch math (validated rounds 2-3):
//   out[u*32+r] = sum_m R[r][u][m] * sum_k L[m][r][k] * in[k*32+m]
// Stage A thread (p,l): T[c] = sum_k L[p][c][k]*V[k*32+p]; cells thread-local.
// Stage B thread (r,l): OUT[u] = sum_m R[r][u][m]*T[r*32+m].
// ---------------------------------------------------------------------------

// p1 tile: [1024][32] fp32, cell(n,l) at n*32 + (l ^ 4*(((n>>2)^(n>>5))&7)).
__device__ __forceinline__ int cell1(int n, int l) {
  return (n << 5) + (l ^ ((((n >> 2) ^ (n >> 5)) & 7) << 2));
}
// p2 tile: [1024][16] fp32, cell(n,l) at n*16 + (l ^ (((n>>1)^(n>>5))&15)).
__device__ __forceinline__ int cell2(int n, int l) {
  return (n << 4) + (l ^ (((n >> 1) ^ (n >> 5)) & 15));
}

__device__ __forceinline__ float dot32(const float* __restrict__ Wrow,
                                       const float (&X)[32]) {
  const float4* w4 = reinterpret_cast<const float4*>(Wrow);
  float acc = 0.f;
#pragma unroll
  for (int q = 0; q < 8; ++q) {
    float4 w = w4[q];
    acc = fmaf(w.x, X[4 * q + 0], acc);
    acc = fmaf(w.y, X[4 * q + 1], acc);
    acc = fmaf(w.z, X[4 * q + 2], acc);
    acc = fmaf(w.w, X[4 * q + 3], acc);
  }
  return acc;
}

struct EpiNone {
  __device__ __forceinline__ void operator()(float&, int) const {}
};
struct EpiReluDK {  // v = relu(v * dk[n]); dk 4KB, L1-broadcast
  const float* dk;
  __device__ __forceinline__ void operator()(float& v, int n) const {
    float a = v * dk[n];
    v = a > 0.f ? a : 0.f;
  }
};

// One monarch over resident vectors. W16=0: p1 layout (l in 0..31);
// W16=1: p2 layout (l in 0..15). p = 0..31. Entry/exit: tile valid, synced.
template <int W16, class Epi>
__device__ __forceinline__ void monarch(float* tile, const float* __restrict__ L,
                                        const float* __restrict__ R, int l, int p,
                                        const Epi epi) {
  // Stage A: thread-local in-place (reads and writes only cells {k*32+p, l}).
  {
    float X[32];
#pragma unroll
    for (int k = 0; k < 32; ++k) {
      const int n = (k << 5) + p;
      X[k] = tile[W16 ? cell2(n, l) : cell1(n, l)];
    }
    const float* Lp = L + (p << 10);
#pragma unroll 2
    for (int c = 0; c < 32; ++c) {
      const int n = (c << 5) + p;
      tile[W16 ? cell2(n, l) : cell1(n, l)] = dot32(Lp + (c << 5), X);
    }
  }
  __syncthreads();  // stage-A writes (all threads) before stage-B row reads
  {
    float M[32];
#pragma unroll
    for (int m = 0; m < 32; ++m) {
      const int n = (p << 5) + m;
      M[m] = tile[W16 ? cell2(n, l) : cell1(n, l)];
    }
    __syncthreads();  // all row reads before cross-thread writes
    const float* Rp = R + (p << 10);
#pragma unroll 2
    for (int u = 0; u < 32; ++u) {
      float acc = dot32(Rp + (u << 5), M);
      const int n = (u << 5) + p;
      epi(acc, n);
      tile[W16 ? cell2(n, l) : cell1(n, l)] = acc;
    }
  }
  __syncthreads();
}

// Phase 1: sequence mixing. grid (32 d-tiles, 32 b), block 1024, 128KB LDS.
__global__ __launch_bounds__(1024, 4) void p1_kernel(
    const float* __restrict__ x, const float* __restrict__ m1L,
    const float* __restrict__ m1R, const float* __restrict__ m2L,
    const float* __restrict__ m2R, const float* __restrict__ nk,
    float* __restrict__ xt_out) {
  __shared__ float tile[1024 * 32];
  const int b = blockIdx.y, d0 = blockIdx.x << 5;
  const int tid = (int)threadIdx.x;
  {  // load x[b, n, d0..d0+31]: 8 full 128B lines per wave-instr
    const int g4 = tid & 7, nn = tid >> 3, l4 = g4 << 2;
    const float* xb = x + ((size_t)b << 20) + d0 + l4;
#pragma unroll
    for (int j = 0; j < 8; ++j) {
      const int n = (j << 7) + nn;
      float4 v = *(const float4*)&xb[(size_t)n << 10];
      *(float4*)&tile[cell1(n, l4)] = v;  // swizzle is 4-aligned: covers l4..l4+3
    }
  }
  __syncthreads();
  const int l = tid & 31, p = tid >> 5;
  monarch<0>(tile, m1L, m1R, l, p, EpiNone());
  {  // relu(nk[d0+ld][n] * v): thread-local cells; nk coalesced 128B/half-wave
    const int q = tid & 31, ld = tid >> 5;
    const float* nkr = nk + ((size_t)(d0 + ld) << 10);
#pragma unroll 4
    for (int j = 0; j < 32; ++j) {
      const int n = (j << 5) + q;
      const int a = cell1(n, ld);
      float v = tile[a] * nkr[n];
      tile[a] = v > 0.f ? v : 0.f;
    }
  }
  __syncthreads();
  monarch<0>(tile, m2L, m2R, l, p, EpiNone());
  {  // store x_tilde: full lines
    const int g4 = tid & 7, nn = tid >> 3, l4 = g4 << 2;
    float* ob = xt_out + ((size_t)b << 20) + d0 + l4;
#pragma unroll
    for (int j = 0; j < 8; ++j) {
      const int n = (j << 7) + nn;
      float4 v = *(const float4*)&tile[cell1(n, l4)];
      *(float4*)&ob[(size_t)n << 10] = v;
    }
  }
}

// Phase 2: dim mixing + residual + LN. grid (64 n-tiles, 32 b), block 512,
// 64KB LDS -> 2 blocks/CU. In-place on d_out (block-exclusive rows; each
// thread's residual reads precede its own stores; threads touch disjoint n).
__global__ __launch_bounds__(512, 4) void p2_kernel(
    const float* xt, const float* __restrict__ m3L,
    const float* __restrict__ m3R, const float* __restrict__ m4L,
    const float* __restrict__ m4R, const float* __restrict__ dk,
    const float* __restrict__ gamma, const float* __restrict__ beta,
    float* out) {
  __shared__ float tile[1024 * 16];
  const int b = blockIdx.y, n0 = blockIdx.x << 4;
  const int tid = (int)threadIdx.x;
  const float* xrows = xt + ((((size_t)b << 10) + n0) << 10);
  {  // transpose-load 16 rows: global 512B contiguous per row-group per instr
    const int c5 = tid & 31, lr = tid >> 5;
    const float* xr = xrows + ((size_t)lr << 10);
#pragma unroll
    for (int j = 0; j < 8; ++j) {
      const int d = (j << 7) + (c5 << 2);
      float4 v = *(const float4*)&xr[d];
      tile[cell2(d + 0, lr)] = v.x;
      tile[cell2(d + 1, lr)] = v.y;
      tile[cell2(d + 2, lr)] = v.z;
      tile[cell2(d + 3, lr)] = v.w;
    }
  }
  __syncthreads();
  const int l = tid & 15, p = tid >> 4;
  monarch<1>(tile, m3L, m3R, l, p, EpiReluDK{dk});
  monarch<1>(tile, m4L, m4R, l, p, EpiNone());
  {  // h = y + xt (coalesced resid re-read); two-pass LN; coalesced store
    const int q = tid & 31, lr = tid >> 5;
    const float* xr = xrows + ((size_t)lr << 10);
    float hb[32];
    float s = 0.f;
#pragma unroll
    for (int j = 0; j < 32; ++j) {
      const int n = (j << 5) + q;
      float hv = tile[cell2(n, lr)] + xr[n];
      hb[j] = hv;
      s += hv;
    }
#pragma unroll
    for (int m = 1; m <= 16; m <<= 1) s += __shfl_xor(s, m);
    const float mu = s * (1.f / 1024.f);
    float vs = 0.f;
#pragma unroll
    for (int j = 0; j < 32; ++j) {
      float d = hb[j] - mu;
      vs = fmaf(d, d, vs);
    }
#pragma unroll
    for (int m = 1; m <= 16; m <<= 1) vs += __shfl_xor(vs, m);
    const float rs = rsqrtf(vs * (1.f / 1024.f) + 1e-5f);
    float* orow = out + ((((size_t)b << 10) + n0 + lr) << 10);
#pragma unroll 4
    for (int j = 0; j < 32; ++j) {
      const int n = (j << 5) + q;
      orow[n] = (hb[j] - mu) * rs * gamma[n] + beta[n];
    }
  }
}

extern "C" void kernel_launch(void* const* d_in, const int* in_sizes, int n_in,
                              void* d_out, int out_size, void* d_ws, size_t ws_size,
                              hipStream_t stream) {
  (void)in_sizes; (void)n_in; (void)out_size; (void)d_ws; (void)ws_size;
  const float* x   = (const float*)d_in[0];
  const float* m1L = (const float*)d_in[1];
  const float* m1R = (const float*)d_in[2];
  const float* m2L = (const float*)d_in[3];
  const float* m2R = (const float*)d_in[4];
  const float* m3L = (const float*)d_in[5];
  const float* m3R = (const float*)d_in[6];
  const float* m4L = (const float*)d_in[7];
  const float* m4R = (const float*)d_in[8];
  const float* nk  = (const float*)d_in[9];
  const float* dk  = (const float*)d_in[10];
  const float* gam = (const float*)d_in[11];
  const float* bet = (const float*)d_in[12];
  float* out = (float*)d_out;

  hipLaunchKernelGGL(p1_kernel, dim3(32, 32), dim3(1024), 0, stream,
                     x, m1L, m1R, m2L, m2R, nk, out);
  hipLaunchKernelGGL(p2_kernel, dim3(64, 32), dim3(512), 0, stream,
                     out, m3L, m3R, m4L, m4R, dk, gam, bet, out);
}